// Round 1
// baseline (1274.019 us; speedup 1.0000x reference)
//
#include <hip/hip_runtime.h>

// Segment-mean pooling: out[g, :] = mean of node_h rows whose (sorted) batch id == g.
// N=2e6, D=128, G=1024. One block per segment; bounds via binary search (sorted input).

__global__ __launch_bounds__(256) void seg_mean_kernel(
    const float* __restrict__ h,
    const int* __restrict__ batch,
    float* __restrict__ out,
    int N) {
  const int g = blockIdx.x;

  // lower_bound(batch, g) and lower_bound(batch, g+1) — wave-uniform, L2/L3 cached.
  int lo = 0, hi = N;
  while (lo < hi) {
    int mid = (lo + hi) >> 1;
    if (batch[mid] < g) lo = mid + 1; else hi = mid;
  }
  const int start = lo;
  hi = N;
  while (lo < hi) {
    int mid = (lo + hi) >> 1;
    if (batch[mid] < g + 1) lo = mid + 1; else hi = mid;
  }
  const int end = lo;
  const int rows = end - start;

  const int tid = threadIdx.x;
  const int c = tid & 31;   // feature quad: features [4c, 4c+4)
  const int r = tid >> 5;   // row slot 0..7

  float4 acc = make_float4(0.f, 0.f, 0.f, 0.f);
  const float* base = h + (size_t)start * 128 + (size_t)c * 4;

  // Unroll x2: two independent float4 loads in flight per thread.
  int i = r;
  for (; i + 8 < rows; i += 16) {
    const float4 v0 = *(const float4*)(base + (size_t)i * 128);
    const float4 v1 = *(const float4*)(base + (size_t)(i + 8) * 128);
    acc.x += v0.x; acc.y += v0.y; acc.z += v0.z; acc.w += v0.w;
    acc.x += v1.x; acc.y += v1.y; acc.z += v1.z; acc.w += v1.w;
  }
  if (i < rows) {
    const float4 v = *(const float4*)(base + (size_t)i * 128);
    acc.x += v.x; acc.y += v.y; acc.z += v.z; acc.w += v.w;
  }

  __shared__ float4 smem[256];
  smem[tid] = acc;
  __syncthreads();

  if (r == 0) {
    float4 s = smem[c];
    #pragma unroll
    for (int k = 1; k < 8; ++k) {
      const float4 v = smem[k * 32 + c];
      s.x += v.x; s.y += v.y; s.z += v.z; s.w += v.w;
    }
    const float inv = 1.0f / (float)(rows > 0 ? rows : 1);
    float4 o;
    o.x = s.x * inv; o.y = s.y * inv; o.z = s.z * inv; o.w = s.w * inv;
    *(float4*)(out + (size_t)g * 128 + (size_t)c * 4) = o;
  }
}

extern "C" void kernel_launch(void* const* d_in, const int* in_sizes, int n_in,
                              void* d_out, int out_size, void* d_ws, size_t ws_size,
                              hipStream_t stream) {
  const float* node_h   = (const float*)d_in[0];
  const int*   batch    = (const int*)d_in[1];
  float*       out      = (float*)d_out;

  const int N = in_sizes[1];          // 2,000,000
  const int D = in_sizes[0] / N;      // 128
  const int G = out_size / D;         // 1024

  seg_mean_kernel<<<G, 256, 0, stream>>>(node_h, batch, out, N);
}